// Round 2
// baseline (294.034 us; speedup 1.0000x reference)
//
#include <hip/hip_runtime.h>
#include <hip/hip_bf16.h>
#include <math.h>

#define BATCH 512
#define EMBED 512
#define NCLS  100000
#define BN 64
#define BK 32
#define KT 16            // 512/32 k-steps
#define NCHUNK 1563      // ceil(100000/64); tail block has 32 valid cols

typedef __attribute__((ext_vector_type(4))) float f32x4;
typedef __attribute__((ext_vector_type(8))) __bf16 bf16x8;

__device__ __forceinline__ unsigned short f2bf(float f) {
  unsigned int u = __builtin_bit_cast(unsigned int, f);
  u += 0x7fffu + ((u >> 16) & 1u);   // RNE
  return (unsigned short)(u >> 16);
}

constexpr float kCOS_M = 0.8775825618903728f;   // cos(0.5)
constexpr float kSIN_M = 0.4794255386042030f;   // sin(0.5)
constexpr float kTHR   = -0.8775825618903728f;  // cos(pi-0.5)
constexpr float kMM    = 0.2397127693021015f;   // sin(pi-0.5)*0.5
constexpr float kSCALE = 64.0f;
#define NEG_BIG (-1.0e30f)

// ---------------- K1: normalize embeddings -> bf16 ----------------
__global__ void knorm_e(const float* __restrict__ E, unsigned short* __restrict__ En) {
  int row = blockIdx.x;
  int l = threadIdx.x;  // 64 lanes, one wave per row
  const float4* src = (const float4*)(E + row * EMBED);
  float4 a = src[l];
  float4 b = src[l + 64];
  float ss = a.x*a.x + a.y*a.y + a.z*a.z + a.w*a.w
           + b.x*b.x + b.y*b.y + b.z*b.z + b.w*b.w;
#pragma unroll
  for (int d = 1; d < 64; d <<= 1) ss += __shfl_xor(ss, d);
  float rn = 1.0f / fmaxf(sqrtf(ss), 1e-12f);
  ushort4 o;
  o.x = f2bf(a.x * rn); o.y = f2bf(a.y * rn); o.z = f2bf(a.z * rn); o.w = f2bf(a.w * rn);
  ((ushort4*)(En + row * EMBED))[l] = o;
  o.x = f2bf(b.x * rn); o.y = f2bf(b.y * rn); o.z = f2bf(b.z * rn); o.w = f2bf(b.w * rn);
  ((ushort4*)(En + row * EMBED))[l + 64] = o;
}

// ---------------- K2: fused GEMM + margin + partial softmax ----------------
// BM=512 (whole batch per block): W read/converted exactly once device-wide.
__global__ __launch_bounds__(512, 4) void kgemm(
    const unsigned short* __restrict__ En, const float* __restrict__ W,
    const int* __restrict__ labels,
    float* __restrict__ pmax, float* __restrict__ psum,
    float* __restrict__ lablog)
{
  __shared__ unsigned short Al[2][BATCH * BK];  // 2 x 32KB
  __shared__ unsigned short Bl[2][BN * BK];     // 2 x 4KB
  __shared__ float rowsum[BN];
  __shared__ int   lab[BATCH];

  int cchunk = blockIdx.x;
  int c0 = cchunk * BN;

  int tid = threadIdx.x;
  int w = tid >> 6, lane = tid & 63;
  int wr = w >> 1, wc = w & 1;            // 4 row-groups x 2 col-groups
  int lr = lane & 15, lg = lane >> 4;

  lab[tid] = labels[tid];

  // A staging: global_load_lds (linear LDS dest), source pre-swizzled so the
  // 16B slot s of row r holds logical k-chunk s ^ ((r>>1)&3)  (involution).
  auto stageA = [&](int buf, int kt) {
#pragma unroll
    for (int i = 0; i < 4; ++i) {
      int q = i * 512 + tid;            // 16B slot index, linear
      int row = q >> 2, s = q & 3;
      int c = s ^ ((row >> 1) & 3);
      const unsigned short* g = En + row * EMBED + kt * BK + c * 8;
      __builtin_amdgcn_global_load_lds(
          (const __attribute__((address_space(1))) void*)g,
          (__attribute__((address_space(3))) void*)((char*)&Al[buf][0] + q * 16),
          16, 0, 0);
    }
  };

  // B: thread t owns 16B (4 f32) of class row br at seg bc; sumsq accumulates
  // in a register across all k-steps (reduced once at the end).
  int br = tid >> 3, bc = tid & 7;
  const float* wseg = W + (size_t)(c0 + br) * EMBED + bc * 4;
  bool bvalid = (c0 + br) < NCLS;
  float ssq = 0.f;

  auto loadB = [&](int kt) -> f32x4 {
    f32x4 v = {0.f, 0.f, 0.f, 0.f};
    if (bvalid) v = *(const f32x4*)(wseg + kt * BK);
    return v;
  };
  auto writeB = [&](int buf, f32x4 v) {
    ssq += v.x * v.x + v.y * v.y + v.z * v.z + v.w * v.w;
    unsigned int u0 = __builtin_bit_cast(unsigned int, v.x) + 0x8000u;
    unsigned int u1 = __builtin_bit_cast(unsigned int, v.y) + 0x8000u;
    unsigned int u2 = __builtin_bit_cast(unsigned int, v.z) + 0x8000u;
    unsigned int u3 = __builtin_bit_cast(unsigned int, v.w) + 0x8000u;
    unsigned int p0 = __builtin_amdgcn_perm(u1, u0, 0x07060302u); // [bf(x),bf(y)]
    unsigned int p1 = __builtin_amdgcn_perm(u3, u2, 0x07060302u); // [bf(z),bf(w)]
    int phys = (bc >> 1) ^ ((br >> 1) & 3);
    char* dst = (char*)&Bl[buf][0] + br * 64 + phys * 16 + (bc & 1) * 8;
    uint2 pk; pk.x = p0; pk.y = p1;
    *(uint2*)dst = pk;
  };

  f32x4 acc[8][2];
#pragma unroll
  for (int m = 0; m < 8; ++m) { acc[m][0] = (f32x4){0,0,0,0}; acc[m][1] = (f32x4){0,0,0,0}; }

  // prologue
  stageA(0, 0);
  { f32x4 v = loadB(0); writeB(0, v); }
  __syncthreads();

  for (int t = 0; t < KT; ++t) {
    int cur = t & 1;
    f32x4 bv;
    if (t + 1 < KT) {
      stageA(cur ^ 1, t + 1);
      bv = loadB(t + 1);                 // issue early, consume after MFMA
    }
    bf16x8 bf_[2];
#pragma unroll
    for (int n = 0; n < 2; ++n) {
      int row = wc * 32 + n * 16 + lr;
      bf_[n] = *(const bf16x8*)((const char*)&Bl[cur][0] + row * 64 +
                                ((lg ^ ((row >> 1) & 3)) << 4));
    }
#pragma unroll
    for (int m = 0; m < 8; ++m) {
      int row = wr * 128 + m * 16 + lr;
      bf16x8 af = *(const bf16x8*)((const char*)&Al[cur][0] + row * 64 +
                                   ((lg ^ ((row >> 1) & 3)) << 4));
      acc[m][0] = __builtin_amdgcn_mfma_f32_16x16x32_bf16(af, bf_[0], acc[m][0], 0, 0, 0);
      acc[m][1] = __builtin_amdgcn_mfma_f32_16x16x32_bf16(af, bf_[1], acc[m][1], 0, 0, 0);
    }
    if (t + 1 < KT) writeB(cur ^ 1, bv);
    __syncthreads();
  }

  // ---- epilogue ----
  // finish per-class sumsq: reduce over the 8 segment-threads (lanes bc=0..7)
  ssq += __shfl_xor(ssq, 1);
  ssq += __shfl_xor(ssq, 2);
  ssq += __shfl_xor(ssq, 4);
  if (bc == 0) rowsum[br] = ssq;
  __syncthreads();

  float* pm2 = (float*)&Al[0][0];   // alias dead A buffer: [2][512]
  float* ps2 = pm2 + 1024;

  float rn_[2];
#pragma unroll
  for (int n = 0; n < 2; ++n) {
    float ss = rowsum[wc * 32 + n * 16 + lr];
    rn_[n] = 1.0f / fmaxf(sqrtf(ss), 1e-12f);
  }

#pragma unroll
  for (int m = 0; m < 8; ++m) {
#pragma unroll
    for (int i = 0; i < 4; ++i) {
      int rloc = wr * 128 + m * 16 + lg * 4 + i;   // C: row=4*(lane>>4)+reg
      int lbl = lab[rloc];
      float lv[2];
#pragma unroll
      for (int n = 0; n < 2; ++n) {
        int cg = c0 + wc * 32 + n * 16 + lr;       // C: col=lane&15
        float cosv = acc[m][n][i] * rn_[n];
        float logit = kSCALE * cosv;
        if (cg == lbl) {
          float cc = fminf(fmaxf(cosv, -1.0f), 1.0f);
          float sine = sqrtf(fmaxf(1.0f - cc * cc, 0.0f));
          float phi = (cosv > kTHR) ? (cosv * kCOS_M - sine * kSIN_M)
                                    : (cosv - kMM);
          logit = kSCALE * phi;
          lablog[rloc] = logit;
        }
        if (cg >= NCLS) logit = NEG_BIG;
        lv[n] = logit;
      }
      float lmax = fmaxf(lv[0], lv[1]);
      lmax = fmaxf(lmax, __shfl_xor(lmax, 1));
      lmax = fmaxf(lmax, __shfl_xor(lmax, 2));
      lmax = fmaxf(lmax, __shfl_xor(lmax, 4));
      lmax = fmaxf(lmax, __shfl_xor(lmax, 8));
      float ls = __expf(lv[0] - lmax) + __expf(lv[1] - lmax);
      ls += __shfl_xor(ls, 1); ls += __shfl_xor(ls, 2);
      ls += __shfl_xor(ls, 4); ls += __shfl_xor(ls, 8);
      if (lr == 0) {
        pm2[wc * 512 + rloc] = lmax;
        ps2[wc * 512 + rloc] = ls;
      }
    }
  }
  __syncthreads();

  // merge the two wave-column halves -> one partial per (row, chunk)
  {
    int row = tid;
    float m0 = pm2[row], m1 = pm2[512 + row];
    float s0 = ps2[row], s1 = ps2[512 + row];
    float M = fmaxf(m0, m1);
    float S = s0 * __expf(m0 - M) + s1 * __expf(m1 - M);
    pmax[(size_t)row * NCHUNK + cchunk] = M;
    psum[(size_t)row * NCHUNK + cchunk] = S;
  }
}

// ---------------- K3: combine partials -> per-row NLL ----------------
__global__ void kcombine(const float* __restrict__ pmax, const float* __restrict__ psum,
                         const float* __restrict__ lablog, float* __restrict__ nll)
{
  int b = blockIdx.x, tid = threadIdx.x;  // 256 threads
  float m = NEG_BIG, s = 0.f;
  for (int j = tid; j < NCHUNK; j += 256) {
    float mj = pmax[(size_t)b * NCHUNK + j];
    float sj = psum[(size_t)b * NCHUNK + j];
    float M = fmaxf(m, mj);
    s = s * __expf(m - M) + sj * __expf(mj - M);
    m = M;
  }
#pragma unroll
  for (int d = 1; d < 64; d <<= 1) {
    float m2 = __shfl_xor(m, d);
    float s2 = __shfl_xor(s, d);
    float M = fmaxf(m, m2);
    s = s * __expf(m - M) + s2 * __expf(m2 - M);
    m = M;
  }
  __shared__ float sm[4], ssh[4];
  if ((tid & 63) == 0) { sm[tid >> 6] = m; ssh[tid >> 6] = s; }
  __syncthreads();
  if (tid == 0) {
    float M = sm[0], S = ssh[0];
    for (int k = 1; k < 4; ++k) {
      float Mn = fmaxf(M, sm[k]);
      S = S * __expf(M - Mn) + ssh[k] * __expf(sm[k] - Mn);
      M = Mn;
    }
    nll[b] = M + __logf(S) - lablog[b];
  }
}

// ---------------- K4: mean ----------------
__global__ void kmean(const float* __restrict__ nll, float* __restrict__ out) {
  int tid = threadIdx.x;  // 512
  float v = nll[tid];
#pragma unroll
  for (int d = 1; d < 64; d <<= 1) v += __shfl_xor(v, d);
  __shared__ float sm[8];
  if ((tid & 63) == 0) sm[tid >> 6] = v;
  __syncthreads();
  if (tid == 0) {
    float t = 0.f;
    for (int k = 0; k < 8; ++k) t += sm[k];
    out[0] = t * (1.0f / 512.0f);
  }
}

extern "C" void kernel_launch(void* const* d_in, const int* in_sizes, int n_in,
                              void* d_out, int out_size, void* d_ws, size_t ws_size,
                              hipStream_t stream)
{
  const float* E      = (const float*)d_in[0];
  const int*   labels = (const int*)d_in[1];
  const float* W      = (const float*)d_in[2];
  float* out = (float*)d_out;

  char* ws = (char*)d_ws;
  unsigned short* En = (unsigned short*)ws;                 // 512*512*2 = 524288 B
  float* pmax   = (float*)(ws + 524288);                    // 512*1563*4 = 3201024 B
  float* psum   = (float*)(ws + 524288 + 3201024);          // 3201024 B
  float* lablog = (float*)(ws + 524288 + 2 * 3201024);      // 2048 B
  float* nll    = lablog + BATCH;                           // 2048 B

  knorm_e <<<BATCH, 64, 0, stream>>>(E, En);
  kgemm   <<<NCHUNK, 512, 0, stream>>>(En, W, labels, pmax, psum, lablog);
  kcombine<<<BATCH, 256, 0, stream>>>(pmax, psum, lablog, nll);
  kmean   <<<1, BATCH, 0, stream>>>(nll, out);
}